// Round 9
// baseline (59.553 us; speedup 1.0000x reference)
//
#include <hip/hip_runtime.h>

#define LRELU(v) ((v) >= 0.f ? (v) : 0.2f*(v))

// ---- conv1: named-register row access ------------------------------------
#define ROROW(P, RB) \
    const float P##0=ro[(RB)+0], P##1=ro[(RB)+1], P##2=ro[(RB)+2], \
        P##3=ro[(RB)+3], P##4=ro[(RB)+4], P##5=ro[(RB)+5], \
        P##6=ro[(RB)+6], P##7=ro[(RB)+7], P##8=ro[(RB)+8];

#define C1X(X0,X1,X2,X3) \
    (wa.x*A##X0 + wa.y*A##X1 + wa.z*A##X2 + wa.w*A##X3 \
   + wb.x*B##X0 + wb.y*B##X1 + wb.z*B##X2 + wb.w*B##X3 \
   + wc.x*C##X0 + wc.y*C##X1 + wc.z*C##X2 + wc.w*C##X3 \
   + wd.x*D##X0 + wd.y*D##X1 + wd.z*D##X2 + wd.w*D##X3)

// ---- conv2: named-register h-row access: E<i> = element i of 36-float row -
#define E0 q0.x
#define E1 q0.y
#define E2 q0.z
#define E3 q0.w
#define E4 q1.x
#define E5 q1.y
#define E6 q1.z
#define E7 q1.w
#define E8 q2.x
#define E9 q2.y
#define E10 q2.z
#define E11 q2.w
#define E12 q3.x
#define E13 q3.y
#define E14 q3.z
#define E15 q3.w
#define E16 q4.x
#define E17 q4.y
#define E18 q4.z
#define E19 q4.w
#define E20 q5.x
#define E21 q5.y
#define E22 q5.z
#define E23 q5.w
#define E24 q6.x
#define E25 q6.y
#define E26 q6.z
#define E27 q6.w
#define E28 q7.x
#define E29 q7.y
#define E30 q7.z
#define E31 q7.w
#define E32 q8.x
#define E33 q8.y
#define E34 q8.z
#define E35 q8.w

// ACC += dot(w, h[eA..eD]) with preprocessor-literal indices
#define AX(ACC, A, B, C, D) ACC += w.x*E##A + w.y*E##B + w.z*E##C + w.w*E##D;

// full 3x3-output block for one ky, weights in w, accs given by bank prefix
#define KY0(P) { AX(P##0, 0,1,2,3)    AX(P##1, 1,2,3,4)    AX(P##2, 2,3,4,5) \
                 AX(P##3, 6,7,8,9)    AX(P##4, 7,8,9,10)   AX(P##5, 8,9,10,11) \
                 AX(P##6, 12,13,14,15) AX(P##7, 13,14,15,16) AX(P##8, 14,15,16,17) }
#define KY1(P) { AX(P##0, 6,7,8,9)    AX(P##1, 7,8,9,10)   AX(P##2, 8,9,10,11) \
                 AX(P##3, 12,13,14,15) AX(P##4, 13,14,15,16) AX(P##5, 14,15,16,17) \
                 AX(P##6, 18,19,20,21) AX(P##7, 19,20,21,22) AX(P##8, 20,21,22,23) }
#define KY2(P) { AX(P##0, 12,13,14,15) AX(P##1, 13,14,15,16) AX(P##2, 14,15,16,17) \
                 AX(P##3, 18,19,20,21) AX(P##4, 19,20,21,22) AX(P##5, 20,21,22,23) \
                 AX(P##6, 24,25,26,27) AX(P##7, 25,26,27,28) AX(P##8, 26,27,28,29) }
#define KY3(P) { AX(P##0, 18,19,20,21) AX(P##1, 19,20,21,22) AX(P##2, 20,21,22,23) \
                 AX(P##3, 24,25,26,27) AX(P##4, 25,26,27,28) AX(P##5, 26,27,28,29) \
                 AX(P##6, 30,31,32,33) AX(P##7, 31,32,33,34) AX(P##8, 32,33,34,35) }

#define RED18(M) \
    a0+=__shfl_xor(a0,M); a1+=__shfl_xor(a1,M); a2+=__shfl_xor(a2,M); \
    a3+=__shfl_xor(a3,M); a4+=__shfl_xor(a4,M); a5+=__shfl_xor(a5,M); \
    a6+=__shfl_xor(a6,M); a7+=__shfl_xor(a7,M); a8+=__shfl_xor(a8,M); \
    b0+=__shfl_xor(b0,M); b1+=__shfl_xor(b1,M); b2+=__shfl_xor(b2,M); \
    b3+=__shfl_xor(b3,M); b4+=__shfl_xor(b4,M); b5+=__shfl_xor(b5,M); \
    b6+=__shfl_xor(b6,M); b7+=__shfl_xor(b7,M); b8+=__shfl_xor(b8,M);

// ---------------- Kernel A: conv stack + f = [hidden(576), |sum(ro)-E|] ----
// Grid 1024: block = (sample n = bid>>1) x (oc-half och = bid&1).
// Thread = (ocp = t>>4: 2 oc each; ich = t&15: ic = ich, ich+16).
// w2 read DIRECTLY from global (L2-resident, no LDS staging, 2 barriers only).
// Partial sums reduced over ich via shfl_xor (lane bits 0-3).
__global__ __launch_bounds__(256) void convf_kernel(
    const float* __restrict__ readout,   // (512,1,9,9)
    const float* __restrict__ energy,    // (512)
    const float* __restrict__ w1,        // (32,1,4,4)
    const float* __restrict__ w2,        // (64,32,4,4)
    const float* __restrict__ W1,        // (32,609)
    float* __restrict__ f_ws,            // (512,577)
    float* __restrict__ W1T)             // (609,32)
{
    const int bid = blockIdx.x;
    const int n   = bid >> 1;
    const int och = bid & 1;
    const int oc0 = och << 5;            // 0 or 32
    const int t = threadIdx.x;
    __shared__ float ro[81];
    __shared__ float h1[1152];           // [ic(32)][pos(36)]

    if (t < 81) ro[t] = readout[n*81 + t];
    __syncthreads();

    // reco_energy (only och=0 blocks, wave 0)
    if (och == 0 && t < 64) {
        float v = ro[t];
        if (t < 17) v += ro[t + 64];
        #pragma unroll
        for (int m = 32; m; m >>= 1) v += __shfl_down(v, m);
        if (t == 0) f_ws[n*577 + 576] = fabsf(v - energy[n]);
    }

    // conv1: thread = (oc1 = t&31, y = t>>5), full 6-wide row; w1 from global
    if (t < 192) {
        const int oc1 = t & 31, y = t >> 5;
        const float4* wp4 = (const float4*)&w1[oc1*16];
        const float4 wa = wp4[0], wb = wp4[1], wc = wp4[2], wd = wp4[3];
        const int rb0 = y*9;
        ROROW(A, rb0)
        ROROW(B, rb0+9)
        ROROW(C, rb0+18)
        ROROW(D, rb0+27)
        float* hp = &h1[oc1*36 + y*6];
        float v;
        v = C1X(0,1,2,3); hp[0] = LRELU(v);
        v = C1X(1,2,3,4); hp[1] = LRELU(v);
        v = C1X(2,3,4,5); hp[2] = LRELU(v);
        v = C1X(3,4,5,6); hp[3] = LRELU(v);
        v = C1X(4,5,6,7); hp[4] = LRELU(v);
        v = C1X(5,6,7,8); hp[5] = LRELU(v);
    }
    __syncthreads();                      // h1 ready

    const int ocp = t >> 4, ich = t & 15;
    const int oca = oc0 + ocp*2, ocb = oca + 1;
    float a0=0.f,a1=0.f,a2=0.f,a3=0.f,a4=0.f,a5=0.f,a6=0.f,a7=0.f,a8=0.f;
    float b0=0.f,b1=0.f,b2=0.f,b3=0.f,b4=0.f,b5=0.f,b6=0.f,b7=0.f,b8=0.f;

    #pragma unroll
    for (int k = 0; k < 2; k++) {
        const int ic = ich + k*16;
        const float4* hp = (const float4*)&h1[ic*36];
        const float4 q0=hp[0], q1=hp[1], q2=hp[2], q3=hp[3], q4=hp[4],
                     q5=hp[5], q6=hp[6], q7=hp[7], q8=hp[8];
        const float4* wpa = (const float4*)&w2[oca*512 + ic*16];
        const float4* wpb = (const float4*)&w2[ocb*512 + ic*16];
        { float4 w = wpa[0]; KY0(a) }
        { float4 w = wpa[1]; KY1(a) }
        { float4 w = wpa[2]; KY2(a) }
        { float4 w = wpa[3]; KY3(a) }
        { float4 w = wpb[0]; KY0(b) }
        { float4 w = wpb[1]; KY1(b) }
        { float4 w = wpb[2]; KY2(b) }
        { float4 w = wpb[3]; KY3(b) }
    }

    // reduce over ich (lane bits 0..3)
    RED18(1) RED18(2) RED18(4) RED18(8)

    if (ich == 0) {
        float* fa = &f_ws[n*577 + oca*9];
        float* fb = &f_ws[n*577 + ocb*9];
        float v;
        v=a0; fa[0]=LRELU(v); v=a1; fa[1]=LRELU(v); v=a2; fa[2]=LRELU(v);
        v=a3; fa[3]=LRELU(v); v=a4; fa[4]=LRELU(v); v=a5; fa[5]=LRELU(v);
        v=a6; fa[6]=LRELU(v); v=a7; fa[7]=LRELU(v); v=a8; fa[8]=LRELU(v);
        v=b0; fb[0]=LRELU(v); v=b1; fb[1]=LRELU(v); v=b2; fb[2]=LRELU(v);
        v=b3; fb[3]=LRELU(v); v=b4; fb[4]=LRELU(v); v=b5; fb[5]=LRELU(v);
        v=b6; fb[6]=LRELU(v); v=b7; fb[7]=LRELU(v); v=b8; fb[8]=LRELU(v);
    }

    // W1 transpose spread over blocks 0..7
    if (bid < 8) {
        for (int idx = t; idx < 2436; idx += 256) {
            const int g = bid*2436 + idx;       // 8*2436 = 609*32
            const int u = g & 31, a = g >> 5;
            W1T[g] = W1[u*609 + a];
        }
    }
}

// ---------------- Kernel B: M = F(512x577) @ T(577x512) -------------------
__global__ __launch_bounds__(256) void mgemm_kernel(
    const float* __restrict__ F,
    const float* __restrict__ T,
    float* __restrict__ M)
{
    const int rb = blockIdx.x >> 3;    // 64 row tiles of 8
    const int cb = blockIdx.x & 7;     // 8 col tiles of 64
    const int t = threadIdx.x;
    const int col = cb*64 + (t & 63);
    const int r0 = rb*8 + (t >> 6)*2;  // wave-uniform
    const int r0u = __builtin_amdgcn_readfirstlane(r0);
    const float* f0 = F + r0u*577;
    const float* f1 = f0 + 577;
    const float* Tc = T + col;
    float a0 = 0.f, a1 = 0.f;
    #pragma unroll 4
    for (int a = 0; a < 576; a += 4) {
        const float t0 = Tc[(a+0)*512];
        const float t1 = Tc[(a+1)*512];
        const float t2 = Tc[(a+2)*512];
        const float t3 = Tc[(a+3)*512];
        a0 += f0[a]*t0 + f0[a+1]*t1 + f0[a+2]*t2 + f0[a+3]*t3;
        a1 += f1[a]*t0 + f1[a+1]*t1 + f1[a+2]*t2 + f1[a+3]*t3;
    }
    { // tail (a == 576)
        const float tv = Tc[576*512];
        a0 += f0[576]*tv;
        a1 += f1[576]*tv;
    }
    M[(r0+0)*512 + col] = a0;
    M[(r0+1)*512 + col] = a1;
}

// ---------------- Kernel C: o_part[isp][j][b] = sum_i exp(-L1) ------------
// grid 1024: jt = bid>>6 (32 j's each), isp = bid&63 (8 i's each)
#define LDM(R0, R1, R2, R3, JOFF) { \
    const float4* p_ = (const float4*)&M[(j0+jl+(JOFF))*512 + b*16]; \
    R0 = p_[0]; R1 = p_[1]; R2 = p_[2]; R3 = p_[3]; }

#define S16(P0, P1, P2, P3) \
  (fabsf(v0.x-P0.x)+fabsf(v0.y-P0.y)+fabsf(v0.z-P0.z)+fabsf(v0.w-P0.w) \
  +fabsf(v1.x-P1.x)+fabsf(v1.y-P1.y)+fabsf(v1.z-P1.z)+fabsf(v1.w-P1.w) \
  +fabsf(v2.x-P2.x)+fabsf(v2.y-P2.y)+fabsf(v2.z-P2.z)+fabsf(v2.w-P2.w) \
  +fabsf(v3.x-P3.x)+fabsf(v3.y-P3.y)+fabsf(v3.z-P3.z)+fabsf(v3.w-P3.w))

__global__ __launch_bounds__(256) void pairwise_kernel(
    const float* __restrict__ M,       // (512,512)
    float* __restrict__ o_part)        // (64,512,32)
{
    const int jt  = blockIdx.x >> 6;
    const int isp = blockIdx.x & 63;
    const int t = threadIdx.x;
    const int b = t & 31, jl = t >> 5;
    const int j0 = jt * 32;
    __shared__ float mi[8*572];        // padded: float off = x + ((x>>5)<<2)

    float4 mA0,mA1,mA2,mA3, mB0,mB1,mB2,mB3, mC0,mC1,mC2,mC3, mD0,mD1,mD2,mD3;
    LDM(mA0,mA1,mA2,mA3, 0)
    LDM(mB0,mB1,mB2,mB3, 8)
    LDM(mC0,mC1,mC2,mC3, 16)
    LDM(mD0,mD1,mD2,mD3, 24)

    // stage 8 i-rows
    const int i0 = isp * 8;
    #pragma unroll
    for (int k = 0; k < 4; k++) {
        const int q = k*256 + t;       // 0..1023
        const int r = q >> 7;
        const int x = (q & 127) * 4;
        float4 v = *(const float4*)&M[(i0+r)*512 + x];
        *(float4*)&mi[r*572 + x + ((x>>5)<<2)] = v;
    }
    __syncthreads();

    float acc0 = 0.f, acc1 = 0.f, acc2 = 0.f, acc3 = 0.f;
    const int lbase = b*16 + ((b>>1)<<2);

    #pragma unroll
    for (int r = 0; r < 8; r++) {
        const float4* q_ = (const float4*)&mi[r*572 + lbase];
        const float4 v0 = q_[0], v1 = q_[1], v2 = q_[2], v3 = q_[3];
        acc0 += __expf(-(S16(mA0,mA1,mA2,mA3)));
        acc1 += __expf(-(S16(mB0,mB1,mB2,mB3)));
        acc2 += __expf(-(S16(mC0,mC1,mC2,mC3)));
        acc3 += __expf(-(S16(mD0,mD1,mD2,mD3)));
    }
    const int ob = isp*16384 + b;
    o_part[ob + (j0+jl   )*32] = acc0;
    o_part[ob + (j0+jl+8 )*32] = acc1;
    o_part[ob + (j0+jl+16)*32] = acc2;
    o_part[ob + (j0+jl+24)*32] = acc3;
}

// ---------------- Kernel D: MLP head, one block per sample -----------------
__global__ __launch_bounds__(256) void mlp_kernel(
    const float* __restrict__ f,       // (512,577)
    const float* __restrict__ o_part,  // (64,512,32)
    const float* __restrict__ W1T,     // (609,32)
    const float* __restrict__ b1,      // (32)
    const float* __restrict__ W2,      // (1,32)
    const float* __restrict__ b2,      // (1)
    float* __restrict__ out)           // (512)
{
    const int j = blockIdx.x;
    const int t = threadIdx.x;
    __shared__ float xs[609];
    __shared__ float red[256];

    for (int a = t; a < 577; a += 256) xs[a] = f[j*577 + a];
    { // o reduction parallel over all 256 threads: (g = t>>5) sums 8 isps
        const int bb = t & 31, g = t >> 5;
        float ov = 0.f;
        #pragma unroll
        for (int k = 0; k < 8; k++)
            ov += o_part[(g + 8*k)*16384 + j*32 + bb];
        red[t] = ov;
    }
    __syncthreads();
    if (t < 32) {
        float ov = 0.f;
        #pragma unroll
        for (int g = 0; g < 8; g++) ov += red[t + g*32];
        xs[577 + t] = ov;
    }
    __syncthreads();

    const int u = t & 31, seg = t >> 5;
    float p = 0.f;
    #pragma unroll 4
    for (int a = seg; a < 609; a += 8)
        p += xs[a] * W1T[a*32 + u];   // xs: LDS broadcast; W1T: coalesced 128B
    red[t] = p;
    __syncthreads();

    if (t < 32) {
        float hid = red[t];
        #pragma unroll
        for (int s = 1; s < 8; s++) hid += red[t + s*32];
        hid += b1[t];
        hid = LRELU(hid);
        float pr = hid * W2[t];
        #pragma unroll
        for (int mk = 16; mk; mk >>= 1) pr += __shfl_xor(pr, mk);
        if (t == 0) out[j] = 1.f / (1.f + __expf(-(pr + b2[0])));
    }
}

extern "C" void kernel_launch(void* const* d_in, const int* in_sizes, int n_in,
                              void* d_out, int out_size, void* d_ws, size_t ws_size,
                              hipStream_t stream) {
    const float* readout = (const float*)d_in[0];
    const float* energy  = (const float*)d_in[1];
    const float* w1      = (const float*)d_in[2];
    const float* w2      = (const float*)d_in[3];
    const float* T       = (const float*)d_in[4];
    const float* W1      = (const float*)d_in[5];
    const float* b1      = (const float*)d_in[6];
    const float* W2      = (const float*)d_in[7];
    const float* b2      = (const float*)d_in[8];
    float* out = (float*)d_out;

    char* ws = (char*)d_ws;
    float* f_ws   = (float*)(ws);                                       // 512*577 f32
    float* M_ws   = (float*)(ws + 512*577*4);                           // 512*512 f32
    float* o_ws   = (float*)(ws + 512*577*4 + 512*512*4);               // 64*512*32 f32
    float* W1T_ws = (float*)(ws + 512*577*4 + 512*512*4 + 64*512*32*4); // 609*32 f32

    convf_kernel   <<<1024, 256, 0, stream>>>(readout, energy, w1, w2, W1, f_ws, W1T_ws);
    mgemm_kernel   <<<512, 256, 0, stream>>>(f_ws, T, M_ws);
    pairwise_kernel<<<1024, 256, 0, stream>>>(M_ws, o_ws);
    mlp_kernel     <<<512, 256, 0, stream>>>(f_ws, o_ws, W1T_ws, b1, W2, b2, out);
}